// Round 12
// baseline (172.175 us; speedup 1.0000x reference)
//
#include <hip/hip_runtime.h>
#include <hip/hip_bf16.h>

#define CC 64
#define HW 9216
#define IMG 96
#define PW 100                // padded width/height
#define SPLITS 8
#define SPLEN 1152            // 9216 / 8
#define ITERS 9               // 1152 / 128 keys per iter
#define SKT_S 72              // sKT row stride (halfwords)
#define SPV_S 132             // sVT / sPS row stride (halfwords)
#define LOG2E 1.44269504f

typedef _Float16 f16;
typedef __attribute__((ext_vector_type(8))) _Float16 f16x8;
typedef __attribute__((ext_vector_type(4))) _Float16 f16x4;
typedef __attribute__((ext_vector_type(4))) float f32x4;

// ---------------- pad x into f16 [64][100*100] image (zero borders of 2)
__global__ __launch_bounds__(256) void prepad_kernel(
    const float* __restrict__ x, f16* __restrict__ xpad)
{
    int i = blockIdx.x * 256 + threadIdx.x;      // 64 * 10000
    if (i >= CC * PW * PW) return;
    int ci = i / (PW * PW), p = i % (PW * PW);
    int r = p / PW, c = p % PW;
    bool inside = (r >= 2 && r < IMG + 2 && c >= 2 && c < IMG + 2);
    float v = inside ? x[ci * HW + (r - 2) * IMG + (c - 2)] : 0.f;
    xpad[i] = (f16)v;
}

// ---------------- FUSED conv: dilated 3x3 (pad=2, dil=2) + 1x1 conv from padded f16 image
// co=1 per block, 4 outputs/thread. The 1x1's center tap (padded h+2, w+2..w+5) is the middle
// of the kh=1 row already loaded. Writes yq (flat chw), kt (K^T), vt (V^T).
__global__ __launch_bounds__(256) void conv_dil_kernel(
    const f16* __restrict__ xpad, const float* __restrict__ dW, const float* __restrict__ db,
    const float* __restrict__ cW, const float* __restrict__ cb,
    f16* __restrict__ yq, f16* __restrict__ kt, f16* __restrict__ vt)
{
    const int co = blockIdx.x / 9, chunk = blockIdx.x % 9;   // grid 64*9
    const int t = threadIdx.x;
    const int m0 = chunk * 1024 + 4 * t;         // multiple of 4, never wraps an image row
    const int h = m0 / IMG, w = m0 % IMG;        // w % 4 == 0
    const int pbase = h * PW + w;
    const float* wco = dW + co * 576;            // block-uniform -> s_load
    const float* cwo = cW + co * CC;

    float a0, a1, a2, a3, v0, v1, v2, v3;
    a0 = a1 = a2 = a3 = db[co];
    v0 = v1 = v2 = v3 = cb[co];
    #pragma unroll 2
    for (int ci = 0; ci < CC; ++ci) {
        const f16* rp0 = xpad + ci * (PW * PW) + pbase;
        const float* wk = wco + ci * 9;
        const float cw = cwo[ci];
        #pragma unroll
        for (int kh = 0; kh < 3; ++kh) {
            const f16* rp = rp0 + kh * (2 * PW);
            f16x4 L0 = *(const f16x4*)(rp);      // padded cols w..w+3 (8B aligned)
            f16x4 L1 = *(const f16x4*)(rp + 4);  //             w+4..w+7
            float e0 = (float)L0.x, e1 = (float)L0.y, e2 = (float)L0.z, e3 = (float)L0.w;
            float e4 = (float)L1.x, e5 = (float)L1.y, e6 = (float)L1.z, e7 = (float)L1.w;
            float w0 = wk[kh * 3 + 0], w1 = wk[kh * 3 + 1], w2 = wk[kh * 3 + 2];
            a0 += w0 * e0 + w1 * e2 + w2 * e4;
            a1 += w0 * e1 + w1 * e3 + w2 * e5;
            a2 += w0 * e2 + w1 * e4 + w2 * e6;
            a3 += w0 * e3 + w1 * e5 + w2 * e7;
            if (kh == 1) {                       // 1x1 conv on center taps
                v0 += cw * e2; v1 += cw * e3; v2 += cw * e4; v3 += cw * e5;
            }
        }
    }
    f16 h0 = (f16)a0, h1 = (f16)a1, h2 = (f16)a2, h3 = (f16)a3;
    *(f16x4*)&yq[co * HW + m0] = (f16x4){h0, h1, h2, h3};   // flat chw (Q layout)
    kt[(m0 + 0) * 64 + co] = h0;                            // K^T[m][c]
    kt[(m0 + 1) * 64 + co] = h1;
    kt[(m0 + 2) * 64 + co] = h2;
    kt[(m0 + 3) * 64 + co] = h3;
    float vs[4] = {v0, v1, v2, v3};
    #pragma unroll
    for (int i = 0; i < 4; ++i) {
        int m = m0 + i;                          // vt[col][row]: V[row=m>>6][col=m&63]
        vt[(m & 63) * HW + co * 144 + (m >> 6)] = (f16)vs[i];
    }
}

// ---------------- MFMA flash attention, S^T scheme, BN=128 keys/iter (9 barriers)
__global__ __launch_bounds__(256, 3) void attn_kernel(
    const f16* __restrict__ kt, const f16* __restrict__ vt, const f16* __restrict__ yq,
    f16* __restrict__ acc_ws, float* __restrict__ m_ws, float* __restrict__ l_ws)
{
    __shared__ f16 sKT[128 * SKT_S];       // [key_local][c]   18.4 KB
    __shared__ f16 sVT[64 * SPV_S];        // [channel][key]   16.9 KB
    __shared__ f16 sPS[4 * 16 * SPV_S];    // per-wave P       16.9 KB
    __shared__ float sAL[4 * 16];          // per-wave alpha[query]

    const int t = threadIdx.x;
    const int L = t & 63, w = t >> 6;
    const int g = L >> 4, c16 = L & 15;
    const int qb = blockIdx.x >> 3, sp = blockIdx.x & 7;
    const int n0 = qb * 64;
    const int mbase = sp * SPLEN;
    f16* psw = (f16*)sPS + w * 16 * SPV_S;

    // Q fragments: Q[row][c] = yq_flat[row*64+c] (raw-reshape semantics)
    f16x8 qa[2];
    #pragma unroll
    for (int kc = 0; kc < 2; ++kc)
        qa[kc] = *(const f16x8*)(yq + (n0 + w * 16 + c16) * 64 + g * 8 + kc * 32);

    float mi = -1e30f;
    float li = 0.f;                        // partial row-sum (this lane's key quarter)
    f32x4 acc[4];
    #pragma unroll
    for (int ct = 0; ct < 4; ++ct) acc[ct] = (f32x4){0.f, 0.f, 0.f, 0.f};

    for (int it = 0; it < ITERS; ++it) {
        const int m0 = mbase + it * 128;
        __syncthreads();
        // stage K^T: 128 rows x 64 ch = 1024 uint4; V^T: 64 rows x 128 keys = 1024 uint4
        #pragma unroll
        for (int rep = 0; rep < 4; ++rep) {
            int idx = t + rep * 256;
            int krow = idx >> 3, kch = idx & 7;
            *(uint4*)&sKT[krow * SKT_S + kch * 8] = *(const uint4*)&kt[(m0 + krow) * 64 + kch * 8];
            int vrow = idx >> 4, vch = idx & 15;
            *(uint4*)&sVT[vrow * SPV_S + vch * 8] = *(const uint4*)&vt[vrow * HW + m0 + vch * 8];
        }
        __syncthreads();

        // S^T = K Q^T : s[mt][j] = S[query w*16+c16][key m0 + mt*16 + 4g + j]
        f32x4 s[8];
        #pragma unroll
        for (int mt = 0; mt < 8; ++mt) {
            f32x4 a0 = (f32x4){0.f, 0.f, 0.f, 0.f};
            #pragma unroll
            for (int kc = 0; kc < 2; ++kc) {
                f16x8 kb = *(const f16x8*)&sKT[(mt * 16 + c16) * SKT_S + g * 8 + kc * 32];
                a0 = __builtin_amdgcn_mfma_f32_16x16x32_f16(kb, qa[kc], a0, 0, 0, 0);
            }
            s[mt] = a0;
        }
        // threshold mask to ZERO
        #pragma unroll
        for (int mt = 0; mt < 8; ++mt)
            #pragma unroll
            for (int j = 0; j < 4; ++j)
                s[mt][j] = (fabsf(s[mt][j]) > 0.3f) ? s[mt][j] : 0.f;

        // local max tree + 2 cross-lane reduces (queries replicated over g)
        float xm[8];
        #pragma unroll
        for (int mt = 0; mt < 8; ++mt)
            xm[mt] = fmaxf(fmaxf(s[mt][0], s[mt][1]), fmaxf(s[mt][2], s[mt][3]));
        float mx = fmaxf(fmaxf(fmaxf(xm[0], xm[1]), fmaxf(xm[2], xm[3])),
                         fmaxf(fmaxf(xm[4], xm[5]), fmaxf(xm[6], xm[7])));
        mx = fmaxf(mx, __shfl_xor(mx, 16, 64));
        mx = fmaxf(mx, __shfl_xor(mx, 32, 64));
        float mnew = fmaxf(mi, mx);
        float nL = mnew * LOG2E;
        float alpha = __builtin_amdgcn_exp2f(mi * LOG2E - nL);
        mi = mnew;

        // p = exp2(s*L2E - nL); per-mt immediate P write (keeps 4 p live), partial li
        float ls = 0.f;
        #pragma unroll
        for (int mt = 0; mt < 8; ++mt) {
            float p0 = __builtin_amdgcn_exp2f(fmaf(s[mt][0], LOG2E, -nL));
            float p1 = __builtin_amdgcn_exp2f(fmaf(s[mt][1], LOG2E, -nL));
            float p2 = __builtin_amdgcn_exp2f(fmaf(s[mt][2], LOG2E, -nL));
            float p3 = __builtin_amdgcn_exp2f(fmaf(s[mt][3], LOG2E, -nL));
            ls += (p0 + p1) + (p2 + p3);
            unsigned u0 = __builtin_bit_cast(unsigned int, __builtin_amdgcn_cvt_pkrtz(p0, p1));
            unsigned u1 = __builtin_bit_cast(unsigned int, __builtin_amdgcn_cvt_pkrtz(p2, p3));
            uint2 uv; uv.x = u0; uv.y = u1;
            *(uint2*)&psw[c16 * SPV_S + mt * 16 + 4 * g] = uv;
        }
        li = li * alpha + ls;

        // alpha distribution: 1 LDS write + 1 b128 broadcast read (same-wave RAW ordered)
        if (g == 0) sAL[w * 16 + c16] = alpha;
        f32x4 aj = *(const f32x4*)&sAL[w * 16 + 4 * g];   // alphas of queries 4g..4g+3
        #pragma unroll
        for (int ct = 0; ct < 4; ++ct)
            #pragma unroll
            for (int j = 0; j < 4; ++j) acc[ct][j] *= aj[j];

        // PV: A = P (K=128 -> 4 frags), B = V^T tile
        f16x8 pa[4];
        #pragma unroll
        for (int kc = 0; kc < 4; ++kc)
            pa[kc] = *(const f16x8*)&psw[c16 * SPV_S + g * 8 + kc * 32];
        #pragma unroll
        for (int ct = 0; ct < 4; ++ct)
            #pragma unroll
            for (int kc = 0; kc < 4; ++kc) {
                f16x8 vb = *(const f16x8*)&sVT[(ct * 16 + c16) * SPV_S + g * 8 + kc * 32];
                acc[ct] = __builtin_amdgcn_mfma_f32_16x16x32_f16(pa[kc], vb, acc[ct], 0, 0, 0);
            }
    }

    // finish partial row-sum (once)
    float li_tot = li;
    li_tot += __shfl_xor(li_tot, 16, 64);
    li_tot += __shfl_xor(li_tot, 32, 64);

    // write partials (no divide; merge kernel combines splits)
    const int base = blockIdx.x;
    #pragma unroll
    for (int ct = 0; ct < 4; ++ct)
        #pragma unroll
        for (int j = 0; j < 4; ++j)
            acc_ws[base * 4096 + (w * 16 + 4 * g + j) * 64 + ct * 16 + c16] = (f16)acc[ct][j];
    if (g == 0) {
        m_ws[base * 64 + w * 16 + c16] = mi;    // unscaled units
        l_ws[base * 64 + w * 16 + c16] = li_tot;
    }
}

// ---------------- merge splits + residual + transpose; grid 576 (16-row sub-tiles)
__global__ __launch_bounds__(256) void merge_kernel(
    const f16* __restrict__ acc_ws, const float* __restrict__ m_ws, const float* __restrict__ l_ws,
    const float* __restrict__ x, float* __restrict__ out)
{
    __shared__ float wsh[SPLITS * 16];
    __shared__ float att[64 * 17];
    const int qb = blockIdx.x >> 2, sub = blockIdx.x & 3;
    const int r0 = sub * 16;
    const int t = threadIdx.x;
    if (t < 16) {
        int row = r0 + t;
        float ms = -1e30f;
        float mv[SPLITS];
        #pragma unroll
        for (int sp = 0; sp < SPLITS; ++sp) {
            mv[sp] = m_ws[(qb * SPLITS + sp) * 64 + row];
            ms = fmaxf(ms, mv[sp]);
        }
        float Lsum = 0.f, ev[SPLITS];
        #pragma unroll
        for (int sp = 0; sp < SPLITS; ++sp) {
            ev[sp] = __builtin_amdgcn_exp2f((mv[sp] - ms) * LOG2E);
            Lsum += l_ws[(qb * SPLITS + sp) * 64 + row] * ev[sp];
        }
        float inv = 1.f / Lsum;
        #pragma unroll
        for (int sp = 0; sp < SPLITS; ++sp)
            wsh[sp * 16 + t] = ev[sp] * inv;
    }
    __syncthreads();
    for (int i = t; i < 1024; i += 256) {
        int rr = i >> 6, c = i & 63;         // c fast -> coalesced acc_ws reads
        float v = 0.f;
        #pragma unroll
        for (int sp = 0; sp < SPLITS; ++sp)
            v += (float)acc_ws[(qb * SPLITS + sp) * 4096 + (r0 + rr) * 64 + c] * wsh[sp * 16 + rr];
        att[c * 17 + rr] = v;
    }
    __syncthreads();
    const int n0 = qb * 64 + r0;
    for (int i = t; i < 1024; i += 256) {
        int c = i >> 4, r = i & 15;
        int idx = c * HW + n0 + r;
        out[idx] = x[idx] + att[c * 17 + r];
    }
}

extern "C" void kernel_launch(void* const* d_in, const int* in_sizes, int n_in,
                              void* d_out, int out_size, void* d_ws, size_t ws_size,
                              hipStream_t stream)
{
    const float* x  = (const float*)d_in[0];
    const float* dW = (const float*)d_in[1];
    const float* db = (const float*)d_in[2];
    const float* cW = (const float*)d_in[3];
    const float* cb = (const float*)d_in[4];
    float* out = (float*)d_out;

    char* ws = (char*)d_ws;
    f16* kt     = (f16*)(ws);                        // 1,179,648 B
    f16* yq     = (f16*)(ws + 1179648);              // 1,179,648 B
    f16* vt     = (f16*)(ws + 2359296);              // 1,179,648 B
    f16* xpad   = (f16*)(ws + 3538944);              // 1,280,000 B
    f16* acc_ws = (f16*)(ws + 4818944);              // 9,437,184 B
    float* m_ws = (float*)(ws + 14256128);           //   294,912 B
    float* l_ws = (float*)(ws + 14551040);           //   294,912 B
                                                     // total 14,845,952 B

    prepad_kernel<<<dim3((CC * PW * PW + 255) / 256), dim3(256), 0, stream>>>(x, xpad);
    conv_dil_kernel<<<dim3(64 * 9), dim3(256), 0, stream>>>(xpad, dW, db, cW, cb, yq, kt, vt);
    attn_kernel<<<dim3(144 * SPLITS), dim3(256), 0, stream>>>(kt, vt, yq, acc_ws, m_ws, l_ws);
    merge_kernel<<<dim3(576), dim3(256), 0, stream>>>(acc_ws, m_ws, l_ws, x, out);
}